// Round 1
// baseline (138.416 us; speedup 1.0000x reference)
//
#include <hip/hip_runtime.h>
#include <stdint.h>

#define VSZ 30000
#define TPS 2048      // trees per side
#define G3  384

// workspace layout (float offsets)
#define OFF_PROJ   0u
#define OFF_WCT    3840000u   // 128*128
#define OFF_WIHTF  3856384u   // 128*384
#define OFF_WIHTB  3905536u   // 128*384
#define OFF_SEQ    3954688u   // 2*2048*128
#define OFF_GI     4478976u   // 2*2*64*32*384
#define OFF_HFIN   10770432u  // 256*128

__device__ __forceinline__ float sigm(float x) { return 1.0f / (1.0f + __expf(-x)); }
__device__ __forceinline__ float tanh_fast(float x) {
  float e = __expf(-2.0f * x);
  return 2.0f / (1.0f + e) - 1.0f;   // safe at both tails (no inf/inf)
}
__device__ __forceinline__ unsigned bf16_rn(float f) {
  unsigned u = __float_as_uint(f);
  return (u + 0x7FFFu + ((u >> 16) & 1u)) >> 16;   // round-to-nearest-even
}
__device__ __forceinline__ float bflo(unsigned u) { return __uint_as_float(u << 16); }
__device__ __forceinline__ float bfhi(unsigned u) { return __uint_as_float(u & 0xFFFF0000u); }

// ---- K0: transpose src[R][128] -> dst[128][R]   (R % 32 == 0)
__global__ __launch_bounds__(256) void k_transpose(const float* __restrict__ src,
                                                   float* __restrict__ dst, int R) {
  __shared__ float tile[32][129];
  int r0 = blockIdx.x * 32;
  for (int idx = threadIdx.x; idx < 32 * 128; idx += 256) {
    int r = idx >> 7, c = idx & 127;
    tile[r][c] = src[(r0 + r) * 128 + c];
  }
  __syncthreads();
  for (int idx = threadIdx.x; idx < 32 * 128; idx += 256) {
    int k = idx >> 5, r = idx & 31;
    dst[k * R + r0 + r] = tile[r][k];
  }
}

// ---- K1: proj[v][eo] = b_c[eo] + sum_k emb[v][k] * w_c[eo][k]  (wcT is [k][eo])
__global__ __launch_bounds__(256) void k_proj(const float* __restrict__ emb,
                                              const float* __restrict__ wcT,
                                              const float* __restrict__ b_c,
                                              float* __restrict__ proj) {
  __shared__ float wT[128 * 128];     // 64 KB, [k][eo]
  __shared__ float es[32][128];       // 16 KB
  int v0 = blockIdx.x * 32;
  for (int idx = threadIdx.x; idx < 128 * 32; idx += 256)
    ((float4*)wT)[idx] = ((const float4*)wcT)[idx];
  for (int idx = threadIdx.x; idx < 32 * 32; idx += 256) {
    int v = idx >> 5;
    float4 val = make_float4(0.f, 0.f, 0.f, 0.f);
    if (v0 + v < VSZ) val = ((const float4*)emb)[v0 * 32 + idx];
    ((float4*)es)[idx] = val;
  }
  __syncthreads();
  int tv = (threadIdx.x >> 5) << 2;   // v base (0..28)
  int te = (threadIdx.x & 31) << 2;   // eo base (0..124)
  float4 bc4 = *(const float4*)&b_c[te];
  float4 a0 = bc4, a1 = bc4, a2 = bc4, a3 = bc4;
#pragma unroll 4
  for (int kk = 0; kk < 128; ++kk) {
    float4 w4 = *(float4*)&wT[kk * 128 + te];
    float e0 = es[tv + 0][kk], e1 = es[tv + 1][kk];
    float e2 = es[tv + 2][kk], e3 = es[tv + 3][kk];
    a0.x = fmaf(e0, w4.x, a0.x); a0.y = fmaf(e0, w4.y, a0.y);
    a0.z = fmaf(e0, w4.z, a0.z); a0.w = fmaf(e0, w4.w, a0.w);
    a1.x = fmaf(e1, w4.x, a1.x); a1.y = fmaf(e1, w4.y, a1.y);
    a1.z = fmaf(e1, w4.z, a1.z); a1.w = fmaf(e1, w4.w, a1.w);
    a2.x = fmaf(e2, w4.x, a2.x); a2.y = fmaf(e2, w4.y, a2.y);
    a2.z = fmaf(e2, w4.z, a2.z); a2.w = fmaf(e2, w4.w, a2.w);
    a3.x = fmaf(e3, w4.x, a3.x); a3.y = fmaf(e3, w4.y, a3.y);
    a3.z = fmaf(e3, w4.z, a3.z); a3.w = fmaf(e3, w4.w, a3.w);
  }
  if (v0 + tv + 0 < VSZ) *(float4*)&proj[(size_t)(v0 + tv + 0) * 128 + te] = a0;
  if (v0 + tv + 1 < VSZ) *(float4*)&proj[(size_t)(v0 + tv + 1) * 128 + te] = a1;
  if (v0 + tv + 2 < VSZ) *(float4*)&proj[(size_t)(v0 + tv + 2) * 128 + te] = a2;
  if (v0 + tv + 3 < VSZ) *(float4*)&proj[(size_t)(v0 + tv + 3) * 128 + te] = a3;
}

// ---- K2: per-tree subtree sums (heap), coord-wise max, ReLU -> seq[side][t][c]
__global__ __launch_bounds__(256) void k_tree(const int* __restrict__ tokens1,
                                              const int* __restrict__ tokens2,
                                              const float* __restrict__ proj,
                                              float* __restrict__ seq) {
  __shared__ int tok[2][64];
  int side = blockIdx.y;
  const int* tokens = side ? tokens2 : tokens1;
  int t0 = blockIdx.x * 2;
  if (threadIdx.x < 128) {
    int tl = threadIdx.x >> 6, j = threadIdx.x & 63;
    tok[tl][j] = tokens[(t0 + tl) * 64 + j];
  }
  __syncthreads();
  int tl = threadIdx.x >> 7;
  int c  = threadIdx.x & 127;
  float s[64];
#pragma unroll
  for (int j = 0; j < 64; ++j) s[j] = proj[(size_t)tok[tl][j] * 128 + c];
  // bottom-up subtree sums: children of j are 2j+1, 2j+2 (node 31 has only 63)
  s[31] += s[63];
#pragma unroll
  for (int j = 30; j >= 0; --j) s[j] += s[2 * j + 1] + s[2 * j + 2];
  float m = s[0];
#pragma unroll
  for (int j = 1; j < 64; ++j) m = fmaxf(m, s[j]);
  m = fmaxf(m, 0.0f);
  seq[(size_t)(side * TPS + t0 + tl) * 128 + c] = m;
}

// ---- K3: gi[side][dir][b][s][r] = b_ih[r] + sum_k seq[side][t][k]*w_ih[r][k]
//      wihT is [k][384]; block computes a 16t x 128r tile
__global__ __launch_bounds__(256) void k_gi(const float* __restrict__ seq,
                                            const float* __restrict__ wihT_f,
                                            const float* __restrict__ wihT_b,
                                            const float* __restrict__ b_ih_f,
                                            const float* __restrict__ b_ih_b,
                                            float* __restrict__ gi) {
  __shared__ float wT[128 * 128];   // [k][r-chunk]
  __shared__ float sq[16][128];
  int ttile = blockIdx.x;           // 0..127
  int rc = blockIdx.y;              // 0..2
  int sd = blockIdx.z;              // side*2+dir
  int side = sd >> 1, dir = sd & 1;
  const float* wihT = dir ? wihT_b : wihT_f;
  const float* b_ih = dir ? b_ih_b : b_ih_f;
  for (int idx = threadIdx.x; idx < 128 * 32; idx += 256) {
    int k = idx >> 5, r4 = idx & 31;
    ((float4*)wT)[idx] = *(const float4*)&wihT[k * G3 + rc * 128 + (r4 << 2)];
  }
  int t0 = ttile * 16;
  const float4* sqsrc = (const float4*)&seq[(size_t)(side * TPS + t0) * 128];
  for (int idx = threadIdx.x; idx < 16 * 32; idx += 256)
    ((float4*)sq)[idx] = sqsrc[idx];
  __syncthreads();
  int tt = threadIdx.x >> 5;        // t-pair 0..7
  int te = (threadIdx.x & 31) << 2; // r base
  float4 b4 = *(const float4*)&b_ih[rc * 128 + te];
  float4 a0 = b4, a1 = b4;
#pragma unroll 4
  for (int kk = 0; kk < 128; ++kk) {
    float4 w4 = *(float4*)&wT[kk * 128 + te];
    float e0 = sq[tt * 2 + 0][kk], e1 = sq[tt * 2 + 1][kk];
    a0.x = fmaf(e0, w4.x, a0.x); a0.y = fmaf(e0, w4.y, a0.y);
    a0.z = fmaf(e0, w4.z, a0.z); a0.w = fmaf(e0, w4.w, a0.w);
    a1.x = fmaf(e1, w4.x, a1.x); a1.y = fmaf(e1, w4.y, a1.y);
    a1.z = fmaf(e1, w4.z, a1.z); a1.w = fmaf(e1, w4.w, a1.w);
  }
#pragma unroll
  for (int i = 0; i < 2; ++i) {
    int t = t0 + tt * 2 + i;
    int b = t >> 5, s = t & 31;
    float4 v = i ? a1 : a0;
    *(float4*)&gi[((size_t)(sd * 64 + b) * 32 + s) * G3 + rc * 128 + te] = v;
  }
}

// ---- K4: 256 independent GRU scans; one block per (side,dir,program).
//      w_hh staged as bf16 in LDS (96 KB) with XOR swizzle; h kept f32.
__global__ __launch_bounds__(384) void k_scan(const float* __restrict__ gi,
                                              const float* __restrict__ w_hh_f,
                                              const float* __restrict__ w_hh_b,
                                              const float* __restrict__ b_hh_f,
                                              const float* __restrict__ b_hh_b,
                                              float* __restrict__ hfin) {
  __shared__ __align__(16) unsigned wlds[G3 * 64];  // 96 KB: row r = 64 u32 (128 bf16)
  __shared__ __align__(16) float hf32[128];
  __shared__ float rr_l[128];
  __shared__ float zz_l[128];
  int scan = blockIdx.x;                 // side*128 + dir*64 + b
  int dir = (scan >> 6) & 1;
  const float* whh = dir ? w_hh_b : w_hh_f;
  const float* bhh = dir ? b_hh_b : b_hh_f;
  int tid = threadIdx.x;
  // stage w_hh -> bf16, swizzled: byte = r*256 + ((kp*4) ^ ((r&7)<<4))
  for (int p = tid; p < G3 * 64; p += 384) {
    int r = p >> 6, kp = p & 63;
    float2 wv = *(const float2*)&whh[r * 128 + kp * 2];
    unsigned u = bf16_rn(wv.x) | (bf16_rn(wv.y) << 16);
    *(unsigned*)((char*)wlds + r * 256 + ((kp * 4) ^ ((r & 7) << 4))) = u;
  }
  if (tid < 128) hf32[tid] = 0.0f;
  int g = tid >> 7;         // gate: 0=r 1=z 2=n  (wave-uniform)
  int c = tid & 127;
  int r = tid;
  float bh = bhh[r];
  const float* gptr = gi + (size_t)scan * (32 * G3);
  const char* wbase = (const char*)wlds + r * 256;
  int sw = (r & 7) << 4;
  __syncthreads();
  for (int s = 0; s < 32; ++s) {
    int sidx = dir ? (31 - s) : s;
    float gv = gptr[sidx * G3 + r];
    float a0 = bh, a1 = 0.f, a2 = 0.f, a3 = 0.f;
#pragma unroll
    for (int kk = 0; kk < 16; ++kk) {
      uint4  wu = *(const uint4*)(wbase + ((kk * 16) ^ sw));
      float4 xa = *(const float4*)&hf32[kk * 8];
      float4 xb = *(const float4*)&hf32[kk * 8 + 4];
      a0 = fmaf(bflo(wu.x), xa.x, a0); a1 = fmaf(bfhi(wu.x), xa.y, a1);
      a2 = fmaf(bflo(wu.y), xa.z, a2); a3 = fmaf(bfhi(wu.y), xa.w, a3);
      a0 = fmaf(bflo(wu.z), xb.x, a0); a1 = fmaf(bfhi(wu.z), xb.y, a1);
      a2 = fmaf(bflo(wu.w), xb.z, a2); a3 = fmaf(bfhi(wu.w), xb.w, a3);
    }
    float gh = (a0 + a1) + (a2 + a3);
    if (g == 0)      rr_l[c] = sigm(gv + gh);
    else if (g == 1) zz_l[c] = sigm(gv + gh);
    __syncthreads();
    if (g == 2) {
      float rv = rr_l[c];
      float nv = tanh_fast(gv + rv * gh);
      float zv = zz_l[c];
      float hn = (1.0f - zv) * nv + zv * hf32[c];
      hf32[c] = hn;
    }
    __syncthreads();
  }
  if (tid < 128) hfin[(size_t)scan * 128 + tid] = hf32[tid];
}

// ---- K5: out[b] = sigmoid(|lvec-rvec| . w_out + b_out)
__global__ __launch_bounds__(64) void k_out(const float* __restrict__ hfin,
                                            const float* __restrict__ w_out,
                                            const float* __restrict__ b_out,
                                            float* __restrict__ out) {
  int b = blockIdx.x, lane = threadIdx.x;
  float p = 0.f;
#pragma unroll
  for (int i = 0; i < 2; ++i) {
    int c = lane + i * 64;
    float l = hfin[(size_t)(0   + b) * 128 + c] + hfin[(size_t)(64  + b) * 128 + c];
    float r = hfin[(size_t)(128 + b) * 128 + c] + hfin[(size_t)(192 + b) * 128 + c];
    p += fabsf(l - r) * w_out[c];
  }
#pragma unroll
  for (int off = 32; off > 0; off >>= 1) p += __shfl_down(p, off);
  if (lane == 0) out[b] = sigm(p + b_out[0]);
}

extern "C" void kernel_launch(void* const* d_in, const int* in_sizes, int n_in,
                              void* d_out, int out_size, void* d_ws, size_t ws_size,
                              hipStream_t stream) {
  (void)in_sizes; (void)n_in; (void)out_size; (void)ws_size;
  const int*   tokens1 = (const int*)d_in[0];
  const int*   tokens2 = (const int*)d_in[2];
  const float* emb     = (const float*)d_in[4];
  const float* w_c     = (const float*)d_in[5];
  const float* b_c     = (const float*)d_in[6];
  const float* w_ih_f  = (const float*)d_in[7];
  const float* w_hh_f  = (const float*)d_in[8];
  const float* b_ih_f  = (const float*)d_in[9];
  const float* b_hh_f  = (const float*)d_in[10];
  const float* w_ih_b  = (const float*)d_in[11];
  const float* w_hh_b  = (const float*)d_in[12];
  const float* b_ih_b  = (const float*)d_in[13];
  const float* b_hh_b  = (const float*)d_in[14];
  const float* w_out   = (const float*)d_in[15];
  const float* b_out   = (const float*)d_in[16];
  float* ws = (float*)d_ws;
  float* proj   = ws + OFF_PROJ;
  float* wcT    = ws + OFF_WCT;
  float* wihT_f = ws + OFF_WIHTF;
  float* wihT_b = ws + OFF_WIHTB;
  float* seq    = ws + OFF_SEQ;
  float* gi     = ws + OFF_GI;
  float* hfin   = ws + OFF_HFIN;

  k_transpose<<<4,  256, 0, stream>>>(w_c,    wcT,    128);
  k_transpose<<<12, 256, 0, stream>>>(w_ih_f, wihT_f, G3);
  k_transpose<<<12, 256, 0, stream>>>(w_ih_b, wihT_b, G3);
  k_proj<<<(VSZ + 31) / 32, 256, 0, stream>>>(emb, wcT, b_c, proj);
  k_tree<<<dim3(TPS / 2, 2), 256, 0, stream>>>(tokens1, tokens2, proj, seq);
  k_gi<<<dim3(128, 3, 4), 256, 0, stream>>>(seq, wihT_f, wihT_b, b_ih_f, b_ih_b, gi);
  k_scan<<<256, 384, 0, stream>>>(gi, w_hh_f, w_hh_b, b_hh_f, b_hh_b, hfin);
  k_out<<<64, 64, 0, stream>>>(hfin, w_out, b_out, (float*)d_out);
}